// Round 5
// baseline (226.808 us; speedup 1.0000x reference)
//
#include <hip/hip_runtime.h>
#include <hip/hip_bf16.h>

#define DIMC 384          // C
#define LL 785            // 1 + 28*28
#define FDIM 1536         // 4*C  (GEMM K)
#define ODIM 768          // 2*C  (GEMM N)
#define NPATCH 196        // 14*14
#define MROWS 12544       // B*196 (GEMM M)
#define BATCH 64

typedef __attribute__((ext_vector_type(8))) short bf16x8;
typedef __attribute__((ext_vector_type(4))) float floatx4;
typedef __attribute__((ext_vector_type(4))) unsigned short ushort4v;

// ws layout (bytes):
//   anorm u16[12544*1536] @ 0           (38,535,168 B)  pre-normalized bf16 A
//   wbf   u16[768*1536]   @ 38535168    ( 2,359,296 B)  bf16(gamma * w_red)
//   bias  f32[768]        @ 40894464    (     3,072 B)  sum_f beta*w_red
//   stats f32[2*12544]    @ 40897536    (   100,352 B)  mu, rsqrt per m-row
#define WS_WBF_OFF   38535168
#define WS_BIAS_OFF  40894464
#define WS_STATS_OFF 40897536

__device__ __forceinline__ unsigned short f2bf(float f) {
  union { float f; unsigned int u; } v; v.f = f;
  unsigned int u = v.u + 0x7fffu + ((v.u >> 16) & 1u);   // RNE
  return (unsigned short)(u >> 16);
}

__device__ __forceinline__ void gload_lds16(const void* g, void* l) {
  __builtin_amdgcn_global_load_lds(
      (const __attribute__((address_space(1))) unsigned int*)g,
      (__attribute__((address_space(3))) unsigned int*)l, 16, 0, 0);
}

// ---------------------------------------------------------------------------
// K1 (block ranges by role):
//  [0,3136)      stats: one wave per m-row. Pure read-reduce (no stores of
//                row data): 6 float4 loads from two contiguous 3KB runs,
//                butterfly, write mu/rs only.
//  [3136,4288)   wbf:  wbf[o][f] = bf16(gamma[f] * w_red[o][f])
//  [4288,4480)   bias: bias[o] = sum_f beta[f] * w_red[o][f]
//  [4480,4672)   cls:  out[b,0,o] = dot(x[b,0,:], w_conv[o,:])
// ---------------------------------------------------------------------------
__global__ __launch_bounds__(256) void k1_kernel(
    const float* __restrict__ x, const float* __restrict__ wred,
    const float* __restrict__ wconv, const float* __restrict__ gamma,
    const float* __restrict__ beta, unsigned short* __restrict__ wbf,
    float* __restrict__ bias, float* __restrict__ stats,
    float* __restrict__ out) {
  const int blk = blockIdx.x;
  const int t = threadIdx.x;
  const int wv = t >> 6;
  const int lane = t & 63;

  if (blk < 3136) {                      // ---- stats ----
    const int m = blk * 4 + wv;          // m-row
    int b = m / NPATCH;
    int n = m - b * NPATCH;
    int i = n / 14;
    int j = n - i * 14;
    const unsigned base =
        ((unsigned)b * LL + 1 + (unsigned)(i * 2) * 28 + (unsigned)(j * 2)) * DIMC;
    const int lane4 = lane * 4;
    float s = 0.f, s2 = 0.f;
#pragma unroll
    for (int h = 0; h < 2; ++h) {
      const unsigned rb = base + (unsigned)h * 28 * DIMC;   // contiguous 768-float run
#pragma unroll
      for (int c = 0; c < 3; ++c) {
        float4 q = *reinterpret_cast<const float4*>(x + rb + lane4 + c * 256);
        s  += q.x + q.y + q.z + q.w;
        s2 += q.x * q.x + q.y * q.y + q.z * q.z + q.w * q.w;
      }
    }
#pragma unroll
    for (int o = 1; o < 64; o <<= 1) {
      s  += __shfl_xor(s, o);
      s2 += __shfl_xor(s2, o);
    }
    if (lane == 0) {
      float mu = s * (1.f / FDIM);
      float var = s2 * (1.f / FDIM) - mu * mu;
      stats[2 * m]     = mu;
      stats[2 * m + 1] = rsqrtf(var + 1e-5f);
    }
  } else if (blk < 4288) {               // ---- wbf = bf16(gamma * w_red) ----
    int idx4 = (blk - 3136) * 256 + t;   // < 294912
    int e0 = idx4 * 4;
    int f = e0 % FDIM;
    float4 wq = *reinterpret_cast<const float4*>(wred + e0);
    float4 g = *reinterpret_cast<const float4*>(gamma + f);
    ushort4v u;
    u.x = f2bf(wq.x * g.x); u.y = f2bf(wq.y * g.y);
    u.z = f2bf(wq.z * g.z); u.w = f2bf(wq.w * g.w);
    *reinterpret_cast<ushort4v*>(wbf + e0) = u;
  } else if (blk < 4480) {               // ---- bias ----
    int o = (blk - 4288) * 4 + wv;       // < 768
    const float* wr = wred + (size_t)o * FDIM;
    float s = 0.f;
#pragma unroll
    for (int c = 0; c < 6; ++c) {
      int f = lane * 4 + c * 256;
      float4 wq = *reinterpret_cast<const float4*>(wr + f);
      float4 be = *reinterpret_cast<const float4*>(beta + f);
      s += wq.x * be.x + wq.y * be.y + wq.z * be.z + wq.w * be.w;
    }
#pragma unroll
    for (int o2 = 32; o2 > 0; o2 >>= 1) s += __shfl_down(s, o2);
    if (lane == 0) bias[o] = s;
  } else {                               // ---- cls ----
    __shared__ float xs[DIMC];
    int idx = blk - 4480;                // < 192
    int b = idx / 3;
    int ch = idx - b * 3;
    for (int c = t; c < DIMC; c += 256) xs[c] = x[(size_t)b * LL * DIMC + c];
    __syncthreads();
    int o = ch * 256 + t;
    const float* wr = wconv + (size_t)o * DIMC;
    float acc = 0.f;
#pragma unroll 4
    for (int c = 0; c < DIMC; c += 4) {
      float4 wq = *reinterpret_cast<const float4*>(wr + c);
      acc += wq.x * xs[c] + wq.y * xs[c + 1] + wq.z * xs[c + 2] + wq.w * xs[c + 3];
    }
    out[(size_t)b * 197 * ODIM + o] = acc;
  }
}

// ---------------------------------------------------------------------------
// K2 (normalize): one wave per HALF m-row. Pure stream: 3 contiguous float4
// loads (one 3KB run = pixel pair (2i+h, 2j|2j+1)), 1 fma + pack per elem,
// 2 contiguous 768B bf16 store segments. No reduction, no gather.
//   half h, local f fl<384 -> f = fl + h*384 ; fl>=384 -> f = fl + 384 + h*384
// ---------------------------------------------------------------------------
__global__ __launch_bounds__(256) void k2_kernel(
    const float* __restrict__ x, const float* __restrict__ stats,
    unsigned short* __restrict__ anorm) {
  const int t = threadIdx.x;
  const int gw = blockIdx.x * 4 + (t >> 6);   // 0..25087
  const int lane = t & 63;
  const int m = gw >> 1;
  const int h = gw & 1;
  int b = m / NPATCH;
  int n = m - b * NPATCH;
  int i = n / 14;
  int j = n - i * 14;
  const unsigned base =
      ((unsigned)b * LL + 1 + (unsigned)(i * 2 + h) * 28 + (unsigned)(j * 2)) * DIMC;
  const int lane4 = lane * 4;

  float4 v[3];
#pragma unroll
  for (int c = 0; c < 3; ++c)
    v[c] = *reinterpret_cast<const float4*>(x + base + lane4 + c * 256);

  float mu = stats[2 * m];
  float rs = stats[2 * m + 1];
  float nmu = -mu * rs;

  unsigned short* arow = anorm + (size_t)m * FDIM + h * 384;
#pragma unroll
  for (int c = 0; c < 3; ++c) {
    int fl = lane4 + c * 256;
    int f = fl + ((fl >= 384) ? 384 : 0);
    union { ushort4v u4; __hip_bfloat162 h2[2]; } u;
    u.h2[0] = __float22bfloat162_rn(make_float2(v[c].x * rs + nmu, v[c].y * rs + nmu));
    u.h2[1] = __float22bfloat162_rn(make_float2(v[c].z * rs + nmu, v[c].w * rs + nmu));
    *reinterpret_cast<ushort4v*>(arow + f) = u.u4;
  }
}

// ---------------------------------------------------------------------------
// GEMM (m97 structure, unchanged from round 4; bank conflicts = 0 verified).
// Tile 128x128, BK=64, 4 waves 2x2, wave = 4x4 of 16x16x32 MFMA.
// global_load_lds width=16, XOR-swizzled LDS chunks, XCD-aware 1-D swizzle.
// ---------------------------------------------------------------------------
__global__ __launch_bounds__(256) void gemm_kernel(
    const unsigned short* __restrict__ anorm,
    const unsigned short* __restrict__ wbf,
    const float* __restrict__ bias, float* __restrict__ out) {
  __shared__ unsigned short As[128 * 64];   // 16 KB
  __shared__ unsigned short Bs[128 * 64];   // 16 KB

  const int t = threadIdx.x;
  int id = blockIdx.x;
  int rb, cb;
  if (id < 576) {
    int g = id / 48;
    int rem = id - g * 48;
    rb = g * 8 + (rem & 7);
    cb = rem >> 3;
  } else {
    int r = id - 576;
    rb = 96 + (r & 1);
    cb = r >> 1;
  }
  const int mBase = rb * 128;
  const int nBase = cb * 128;

  const unsigned short* agp[4];
  const unsigned short* bgp[4];
  unsigned int ldsoff[4];
#pragma unroll
  for (int p = 0; p < 4; ++p) {
    int s = p * 256 + t;
    int r = s >> 3;
    int cs = (s & 7) ^ (r & 7);
    agp[p] = anorm + (size_t)(mBase + r) * FDIM + cs * 8;
    bgp[p] = wbf + (size_t)(nBase + r) * FDIM + cs * 8;
    ldsoff[p] = (unsigned)s * 8;
  }

  const int wv = t >> 6;
  const int lane = t & 63;
  const int ln15 = lane & 15;
  const int quad = lane >> 4;
  const int wm = wv >> 1;
  const int wn = wv & 1;

  unsigned int aoff[4][2], boff[4][2];
#pragma unroll
  for (int mt = 0; mt < 4; ++mt) {
#pragma unroll
    for (int h = 0; h < 2; ++h) {
      int rA = wm * 64 + mt * 16 + ln15;
      aoff[mt][h] = (unsigned)(rA * 64 + (((h * 4 + quad) ^ (rA & 7)) * 8));
      int rB = wn * 64 + mt * 16 + ln15;
      boff[mt][h] = (unsigned)(rB * 64 + (((h * 4 + quad) ^ (rB & 7)) * 8));
    }
  }

  floatx4 acc[4][4];
#pragma unroll
  for (int mt = 0; mt < 4; ++mt)
#pragma unroll
    for (int nt = 0; nt < 4; ++nt)
      acc[mt][nt] = floatx4{0.f, 0.f, 0.f, 0.f};

  for (int kt = 0; kt < FDIM / 64; ++kt) {
    if (kt) __syncthreads();
#pragma unroll
    for (int p = 0; p < 4; ++p) {
      gload_lds16(agp[p], &As[ldsoff[p]]);
      gload_lds16(bgp[p], &Bs[ldsoff[p]]);
      agp[p] += 64;
      bgp[p] += 64;
    }
    __syncthreads();

#pragma unroll
    for (int h = 0; h < 2; ++h) {
      bf16x8 af[4], bfr[4];
#pragma unroll
      for (int mt = 0; mt < 4; ++mt)
        af[mt] = *reinterpret_cast<const bf16x8*>(&As[aoff[mt][h]]);
#pragma unroll
      for (int nt = 0; nt < 4; ++nt)
        bfr[nt] = *reinterpret_cast<const bf16x8*>(&Bs[boff[nt][h]]);
#pragma unroll
      for (int mt = 0; mt < 4; ++mt)
#pragma unroll
        for (int nt = 0; nt < 4; ++nt)
          acc[mt][nt] = __builtin_amdgcn_mfma_f32_16x16x32_bf16(
              af[mt], bfr[nt], acc[mt][nt], 0, 0, 0);
    }
  }

  float bs[4];
#pragma unroll
  for (int nt = 0; nt < 4; ++nt)
    bs[nt] = bias[nBase + wn * 64 + nt * 16 + ln15];
#pragma unroll
  for (int mt = 0; mt < 4; ++mt) {
#pragma unroll
    for (int r = 0; r < 4; ++r) {
      int m = mBase + wm * 64 + mt * 16 + quad * 4 + r;
      int b = m / NPATCH;
      int n = m - b * NPATCH;
      float* orow = out + ((size_t)b * 197 + 1 + n) * ODIM + nBase + wn * 64;
#pragma unroll
      for (int nt = 0; nt < 4; ++nt)
        orow[nt * 16 + ln15] = acc[mt][nt][r] + bs[nt];
    }
  }
}

extern "C" void kernel_launch(void* const* d_in, const int* in_sizes, int n_in,
                              void* d_out, int out_size, void* d_ws, size_t ws_size,
                              hipStream_t stream) {
  const float* x     = (const float*)d_in[0];   // (64, 785, 384)
  const float* wred  = (const float*)d_in[1];   // (768, 1536)
  const float* wconv = (const float*)d_in[2];   // (768, 384)
  const float* gamma = (const float*)d_in[3];   // (1536,)
  const float* beta  = (const float*)d_in[4];   // (1536,)
  float* out = (float*)d_out;                   // (64, 197, 768)

  unsigned short* anorm = (unsigned short*)d_ws;
  unsigned short* wbf   = (unsigned short*)((char*)d_ws + WS_WBF_OFF);
  float* bias           = (float*)((char*)d_ws + WS_BIAS_OFF);
  float* stats          = (float*)((char*)d_ws + WS_STATS_OFF);

  k1_kernel<<<dim3(4672), 256, 0, stream>>>(x, wred, wconv, gamma, beta,
                                            wbf, bias, stats, out);
  k2_kernel<<<dim3(6272), 256, 0, stream>>>(x, stats, anorm);
  gemm_kernel<<<dim3(588), 256, 0, stream>>>(anorm, wbf, bias, out);
}

// Round 6
// 213.653 us; speedup vs baseline: 1.0616x; 1.0616x over previous
//
#include <hip/hip_runtime.h>
#include <hip/hip_bf16.h>

#define DIMC 384          // C
#define LL 785            // 1 + 28*28
#define FDIM 1536         // 4*C  (GEMM K)
#define ODIM 768          // 2*C  (GEMM N)
#define NPATCH 196        // 14*14
#define MROWS 12544       // B*196 (GEMM M)
#define BATCH 64

typedef __attribute__((ext_vector_type(8))) short bf16x8;
typedef __attribute__((ext_vector_type(4))) float floatx4;
typedef __attribute__((ext_vector_type(4))) unsigned short ushort4v;

// ws layout (bytes):
//   anorm u16[12544*1536] @ 0           (38,535,168 B)  pre-normalized bf16 A
//   wbf   u16[768*1536]   @ 38535168    ( 2,359,296 B)  bf16(gamma * w_red)
//   bias  f32[768]        @ 40894464    (     3,072 B)  sum_f beta*w_red
#define WS_WBF_OFF   38535168
#define WS_BIAS_OFF  40894464

// prep block ranges
#define NB_NORM 784                       // 3136 waves, 4 rows each
#define NB_WBF  288                       // 4 items per thread
#define NB_BIAS 32                        // 128 waves, 6 outputs each
#define NB_CLS  48                        // 4 (b,chunk) items per block
#define PREP_GRID (NB_NORM + NB_WBF + NB_BIAS + NB_CLS)   // 1152

__device__ __forceinline__ unsigned short f2bf(float f) {
  union { float f; unsigned int u; } v; v.f = f;
  unsigned int u = v.u + 0x7fffu + ((v.u >> 16) & 1u);   // RNE
  return (unsigned short)(u >> 16);
}

__device__ __forceinline__ void gload_lds16(const void* g, void* l) {
  __builtin_amdgcn_global_load_lds(
      (const __attribute__((address_space(1))) unsigned int*)g,
      (__attribute__((address_space(3))) unsigned int*)l, 16, 0, 0);
}

// base fp32 offset of m-row's first pixel run (pixels (2i,2j),(2i,2j+1))
__device__ __forceinline__ unsigned rowbase(int m) {
  int b = m / NPATCH;
  int n = m - b * NPATCH;
  int i = n / 14;
  int j = n - i * 14;
  return ((unsigned)b * LL + 1 + (unsigned)(i * 2) * 28 + (unsigned)(j * 2)) * DIMC;
}

// ---------------------------------------------------------------------------
// Prep kernel — persistent waves with grid-stride loops (block ranges by role)
//  [0,784)        norm: wave-per-row, 4 rows/wave (stride 3136), pipelined:
//                 next row's 6 loads issued before current row's butterfly.
//                 Loads: two contiguous 3KB runs; store-side quadrant reorder.
//  [784,1072)     wbf:  4 independent float4 items per thread, unrolled.
//  [1072,1104)    bias: wave handles 6 outputs (2 interleaved chains).
//  [1104,1152)    cls:  4 (b,chunk) items per block.
// ---------------------------------------------------------------------------
__global__ __launch_bounds__(256) void prep_kernel(
    const float* __restrict__ x, const float* __restrict__ wred,
    const float* __restrict__ wconv, const float* __restrict__ gamma,
    const float* __restrict__ beta, unsigned short* __restrict__ anorm,
    unsigned short* __restrict__ wbf, float* __restrict__ bias,
    float* __restrict__ out) {
  const int blk = blockIdx.x;
  const int t = threadIdx.x;
  const int wv = t >> 6;
  const int lane = t & 63;
  const int lane4 = lane * 4;

  if (blk < NB_NORM) {                   // ---- norm: 4 rows per wave ----
    const int w0 = blk * 4 + wv;         // 0..3135
    float4 cur[6], nxt[6];
    unsigned base = rowbase(w0);
#pragma unroll
    for (int c = 0; c < 3; ++c) {
      cur[c]     = *reinterpret_cast<const float4*>(x + base + lane4 + c * 256);
      cur[3 + c] = *reinterpret_cast<const float4*>(x + base + 28 * DIMC + lane4 + c * 256);
    }
#pragma unroll
    for (int it = 0; it < 4; ++it) {
      const int m = w0 + it * 3136;
      if (it < 3) {                      // prefetch next row before reduce
        unsigned nb = rowbase(m + 3136);
#pragma unroll
        for (int c = 0; c < 3; ++c) {
          nxt[c]     = *reinterpret_cast<const float4*>(x + nb + lane4 + c * 256);
          nxt[3 + c] = *reinterpret_cast<const float4*>(x + nb + 28 * DIMC + lane4 + c * 256);
        }
      }
      float s = 0.f, s2 = 0.f;
#pragma unroll
      for (int c = 0; c < 6; ++c) {
        float4 q = cur[c];
        s  += q.x + q.y + q.z + q.w;
        s2 += q.x * q.x + q.y * q.y + q.z * q.z + q.w * q.w;
      }
#pragma unroll
      for (int o = 1; o < 64; o <<= 1) {
        s  += __shfl_xor(s, o);
        s2 += __shfl_xor(s2, o);
      }
      float mu = s * (1.f / FDIM);
      float var = s2 * (1.f / FDIM) - mu * mu;
      float rs = rsqrtf(var + 1e-5f);
      float nmu = -mu * rs;
      unsigned short* arow = anorm + (size_t)m * FDIM;
      // chunk c: run h = c/3 (pixel 2i+... wait: runs are (2i,2j|2j+1) for
      // c<3 and (2i+1,2j|2j+1) for c>=3); local fl = lane4 + (c%3)*256;
      // fl<384 -> first pixel of run, fl>=384 -> second pixel.
      // f = fl + (fl>=384 ? 384 : 0) + (c>=3 ? 384 : 0)
#pragma unroll
      for (int c = 0; c < 6; ++c) {
        int fl = lane4 + (c % 3) * 256;
        int f = fl + ((fl >= 384) ? 384 : 0) + ((c >= 3) ? 384 : 0);
        float4 q = cur[c];
        union { ushort4v u4; __hip_bfloat162 h2[2]; } u;
        u.h2[0] = __float22bfloat162_rn(make_float2(q.x * rs + nmu, q.y * rs + nmu));
        u.h2[1] = __float22bfloat162_rn(make_float2(q.z * rs + nmu, q.w * rs + nmu));
        *reinterpret_cast<ushort4v*>(arow + f) = u.u4;
      }
      if (it < 3) {
#pragma unroll
        for (int c = 0; c < 6; ++c) cur[c] = nxt[c];
      }
    }
  } else if (blk < NB_NORM + NB_WBF) {   // ---- wbf = bf16(gamma*w_red) ----
    const int i0 = (blk - NB_NORM) * 256 + t;   // stride 73728, 4 items
#pragma unroll
    for (int it = 0; it < 4; ++it) {
      int e0 = (i0 + it * 73728) * 4;
      int f = e0 % FDIM;
      float4 wq = *reinterpret_cast<const float4*>(wred + e0);
      float4 g = *reinterpret_cast<const float4*>(gamma + f);
      ushort4v u;
      u.x = f2bf(wq.x * g.x); u.y = f2bf(wq.y * g.y);
      u.z = f2bf(wq.z * g.z); u.w = f2bf(wq.w * g.w);
      *reinterpret_cast<ushort4v*>(wbf + e0) = u;
    }
  } else if (blk < NB_NORM + NB_WBF + NB_BIAS) {   // ---- bias ----
    const int w0 = (blk - NB_NORM - NB_WBF) * 4 + wv;   // 0..127
#pragma unroll
    for (int pair = 0; pair < 3; ++pair) {
      int o0 = w0 * 6 + pair * 2;
      const float* wr0 = wred + (size_t)o0 * FDIM;
      const float* wr1 = wred + (size_t)(o0 + 1) * FDIM;
      float sa = 0.f, sb = 0.f;
#pragma unroll
      for (int c = 0; c < 6; ++c) {
        int f = lane4 + c * 256;
        float4 be = *reinterpret_cast<const float4*>(beta + f);
        float4 wa = *reinterpret_cast<const float4*>(wr0 + f);
        float4 wb = *reinterpret_cast<const float4*>(wr1 + f);
        sa += wa.x * be.x + wa.y * be.y + wa.z * be.z + wa.w * be.w;
        sb += wb.x * be.x + wb.y * be.y + wb.z * be.z + wb.w * be.w;
      }
#pragma unroll
      for (int o = 32; o > 0; o >>= 1) {
        sa += __shfl_down(sa, o);
        sb += __shfl_down(sb, o);
      }
      if (lane == 0) { bias[o0] = sa; bias[o0 + 1] = sb; }
    }
  } else {                               // ---- cls ----
    __shared__ float xs[DIMC];
    const int blk0 = blk - NB_NORM - NB_WBF - NB_BIAS;  // 0..47
#pragma unroll
    for (int it = 0; it < 4; ++it) {
      int idx = blk0 * 4 + it * 192 / 4 * 0 + it * 48;  // idx = blk0 + it*48
      idx = blk0 + it * 48;              // 0..191
      int b = idx / 3;
      int ch = idx - b * 3;
      __syncthreads();
      for (int c = t; c < DIMC; c += 256) xs[c] = x[(size_t)b * LL * DIMC + c];
      __syncthreads();
      int o = ch * 256 + t;
      const float* wr = wconv + (size_t)o * DIMC;
      float acc = 0.f;
#pragma unroll 4
      for (int c = 0; c < DIMC; c += 4) {
        float4 wq = *reinterpret_cast<const float4*>(wr + c);
        acc += wq.x * xs[c] + wq.y * xs[c + 1] + wq.z * xs[c + 2] + wq.w * xs[c + 3];
      }
      out[(size_t)b * 197 * ODIM + o] = acc;
    }
  }
}

// ---------------------------------------------------------------------------
// GEMM (m97 structure, unchanged; bank conflicts = 0 verified round 3).
// Tile 128x128, BK=64, 4 waves 2x2, wave = 4x4 of 16x16x32 MFMA.
// global_load_lds width=16, XOR-swizzled LDS chunks, XCD-aware 1-D swizzle.
// ---------------------------------------------------------------------------
__global__ __launch_bounds__(256) void gemm_kernel(
    const unsigned short* __restrict__ anorm,
    const unsigned short* __restrict__ wbf,
    const float* __restrict__ bias, float* __restrict__ out) {
  __shared__ unsigned short As[128 * 64];   // 16 KB
  __shared__ unsigned short Bs[128 * 64];   // 16 KB

  const int t = threadIdx.x;
  int id = blockIdx.x;
  int rb, cb;
  if (id < 576) {
    int g = id / 48;
    int rem = id - g * 48;
    rb = g * 8 + (rem & 7);
    cb = rem >> 3;
  } else {
    int r = id - 576;
    rb = 96 + (r & 1);
    cb = r >> 1;
  }
  const int mBase = rb * 128;
  const int nBase = cb * 128;

  const unsigned short* agp[4];
  const unsigned short* bgp[4];
  unsigned int ldsoff[4];
#pragma unroll
  for (int p = 0; p < 4; ++p) {
    int s = p * 256 + t;
    int r = s >> 3;
    int cs = (s & 7) ^ (r & 7);
    agp[p] = anorm + (size_t)(mBase + r) * FDIM + cs * 8;
    bgp[p] = wbf + (size_t)(nBase + r) * FDIM + cs * 8;
    ldsoff[p] = (unsigned)s * 8;
  }

  const int wv = t >> 6;
  const int lane = t & 63;
  const int ln15 = lane & 15;
  const int quad = lane >> 4;
  const int wm = wv >> 1;
  const int wn = wv & 1;

  unsigned int aoff[4][2], boff[4][2];
#pragma unroll
  for (int mt = 0; mt < 4; ++mt) {
#pragma unroll
    for (int h = 0; h < 2; ++h) {
      int rA = wm * 64 + mt * 16 + ln15;
      aoff[mt][h] = (unsigned)(rA * 64 + (((h * 4 + quad) ^ (rA & 7)) * 8));
      int rB = wn * 64 + mt * 16 + ln15;
      boff[mt][h] = (unsigned)(rB * 64 + (((h * 4 + quad) ^ (rB & 7)) * 8));
    }
  }

  floatx4 acc[4][4];
#pragma unroll
  for (int mt = 0; mt < 4; ++mt)
#pragma unroll
    for (int nt = 0; nt < 4; ++nt)
      acc[mt][nt] = floatx4{0.f, 0.f, 0.f, 0.f};

  for (int kt = 0; kt < FDIM / 64; ++kt) {
    if (kt) __syncthreads();
#pragma unroll
    for (int p = 0; p < 4; ++p) {
      gload_lds16(agp[p], &As[ldsoff[p]]);
      gload_lds16(bgp[p], &Bs[ldsoff[p]]);
      agp[p] += 64;
      bgp[p] += 64;
    }
    __syncthreads();

#pragma unroll
    for (int h = 0; h < 2; ++h) {
      bf16x8 af[4], bfr[4];
#pragma unroll
      for (int mt = 0; mt < 4; ++mt)
        af[mt] = *reinterpret_cast<const bf16x8*>(&As[aoff[mt][h]]);
#pragma unroll
      for (int nt = 0; nt < 4; ++nt)
        bfr[nt] = *reinterpret_cast<const bf16x8*>(&Bs[boff[nt][h]]);
#pragma unroll
      for (int mt = 0; mt < 4; ++mt)
#pragma unroll
        for (int nt = 0; nt < 4; ++nt)
          acc[mt][nt] = __builtin_amdgcn_mfma_f32_16x16x32_bf16(
              af[mt], bfr[nt], acc[mt][nt], 0, 0, 0);
    }
  }

  float bs[4];
#pragma unroll
  for (int nt = 0; nt < 4; ++nt)
    bs[nt] = bias[nBase + wn * 64 + nt * 16 + ln15];
#pragma unroll
  for (int mt = 0; mt < 4; ++mt) {
#pragma unroll
    for (int r = 0; r < 4; ++r) {
      int m = mBase + wm * 64 + mt * 16 + quad * 4 + r;
      int b = m / NPATCH;
      int n = m - b * NPATCH;
      float* orow = out + ((size_t)b * 197 + 1 + n) * ODIM + nBase + wn * 64;
#pragma unroll
      for (int nt = 0; nt < 4; ++nt)
        orow[nt * 16 + ln15] = acc[mt][nt][r] + bs[nt];
    }
  }
}

extern "C" void kernel_launch(void* const* d_in, const int* in_sizes, int n_in,
                              void* d_out, int out_size, void* d_ws, size_t ws_size,
                              hipStream_t stream) {
  const float* x     = (const float*)d_in[0];   // (64, 785, 384)
  const float* wred  = (const float*)d_in[1];   // (768, 1536)
  const float* wconv = (const float*)d_in[2];   // (768, 384)
  const float* gamma = (const float*)d_in[3];   // (1536,)
  const float* beta  = (const float*)d_in[4];   // (1536,)
  float* out = (float*)d_out;                   // (64, 197, 768)

  unsigned short* anorm = (unsigned short*)d_ws;
  unsigned short* wbf   = (unsigned short*)((char*)d_ws + WS_WBF_OFF);
  float* bias           = (float*)((char*)d_ws + WS_BIAS_OFF);

  prep_kernel<<<dim3(PREP_GRID), 256, 0, stream>>>(x, wred, wconv, gamma, beta,
                                                   anorm, wbf, bias, out);
  gemm_kernel<<<dim3(588), 256, 0, stream>>>(anorm, wbf, bias, out);
}